// Round 8
// baseline (128.864 us; speedup 1.0000x reference)
//
#include <hip/hip_runtime.h>

#define S 128
#define BROWS 8                            // rows per wave band
#define WPB 4                              // waves per block
#define NPLANES 1024                       // B*C
#define TOTAL_WAVES (NPLANES * (S / BROWS))     // 16384
#define NBLOCKS (TOTAL_WAVES / WPB)             // 4096

typedef const __attribute__((address_space(1))) void* gas_t;
typedef __attribute__((address_space(3))) void* las_t;

__global__ __launch_bounds__(256, 4) void pairwise_potential_kernel(
    const float* __restrict__ x, const float* __restrict__ w1,
    const float* __restrict__ w2, float* __restrict__ out)
{
    __shared__ float tile[WPB][10][S];     // 4 x 5120 B, one slice per wave

    const int tid = threadIdx.x;
    const int wid = tid >> 6;      // wave id
    const int l   = tid & 63;      // lane
    const int qc  = l & 31;        // quad-column 0..31
    const int rg  = l >> 5;        // row group (0: rows 0-3, 1: rows 4-7 of band)

    const int gw    = blockIdx.x * WPB + wid;    // global wave id
    const int plane = gw >> 4;                   // 16 bands/plane
    const int band  = gw & 15;
    const int r0    = band * BROWS;
    const int c     = plane & 63;
    const int col   = qc * 4;
    const int rbase = r0 + rg * 4;               // first of this thread's 4 rows
    const int st    = min(max(r0 - 1, 0), S - 10);   // first staged row (10 contiguous)

    const float* xp  = x  + ((size_t)plane << 14);
    const float* w1p = w1 + (size_t)c * (S * S);
    const float* w2p = w2 + (size_t)c * (S * S);

    // ---- burst: 8 w-loads + 5 LDS-staging loads, one wave-private drain ----
    float4 w1v[4], w2v[4];
    #pragma unroll
    for (int q = 0; q < 4; ++q) {
        w1v[q] = *(const float4*)(w1p + (rbase + q) * S + col);
        w2v[q] = *(const float4*)(w2p + (rbase + q) * S + col);
    }
    #pragma unroll
    for (int k = 0; k < 5; ++k) {          // 2 contiguous rows per issue (1 KB)
        const float* src = xp + (st + 2 * k) * S + l * 4;
        __builtin_amdgcn_global_load_lds((gas_t)src, (las_t)&tile[wid][2 * k][0], 16, 0, 0);
    }
    asm volatile("s_waitcnt vmcnt(0)" ::: "memory");   // wave-private; no s_barrier

    // ---- 6 window rows from own LDS slice (+ shfl halo) ----
    float m[6][6];     // [winrow][0..5] = [left | q0 q1 q2 q3 | right]
    #pragma unroll
    for (int j = 0; j < 6; ++j) {
        int lr = rbase - 1 + j - st;             // local tile row
        lr = min(max(lr, 0), 9);                 // clamp; out-of-plane masked below
        const float4 v = *(const float4*)&tile[wid][lr][col];
        float lf = __shfl(v.w, (l - 1) & 63, 64);
        float rf = __shfl(v.x, (l + 1) & 63, 64);
        if (qc == 0)  lf = 0.f;                  // col -1 zero-pad
        if (qc == 31) rf = 0.f;                  // col 128 zero-pad
        m[j][0] = lf; m[j][1] = v.x; m[j][2] = v.y; m[j][3] = v.z; m[j][4] = v.w; m[j][5] = rf;
    }
    if (rbase == 0) {                            // x row -1
        #pragma unroll
        for (int t = 0; t < 6; ++t) m[0][t] = 0.f;
    }
    if (rbase + 4 == S) {                        // x row 128
        #pragma unroll
        for (int t = 0; t < 6; ++t) m[5][t] = 0.f;
    }

    const float NL  = -0.72134752044f;    // -0.5 * log2(e)
    const float E1N = 0.06739229552f;     // exp(-0.5)/9        (d = 1)
    const float E2N = 0.05478541015f;     // exp(-sqrt2/2)/9    (d = sqrt2)
    const float C9  = 0.11111111111f;     // exp(0)/9           (center term)
    const float W2C = 1.07298380550f;     // (4 + 4*sqrt(2)) / 9

    float* op = out + ((size_t)plane << 14) + rbase * S + col;
    #pragma unroll
    for (int q = 0; q < 4; ++q) {
        const float* m0 = m[q];
        const float* m1 = m[q + 1];
        const float* m2 = m[q + 2];
        const float* w1a = &w1v[q].x;
        const float* w2a = &w2v[q].x;
        float4 o;
        float* ov = &o.x;
        #pragma unroll
        for (int k = 0; k < 4; ++k) {
            const float cen = m0[k];      // X(h-1, w-1): window root
            float d;
            d = cen - m0[k + 1]; const float a0 = __builtin_amdgcn_exp2f(d * d * NL);
            d = cen - m0[k + 2]; const float a1 = __builtin_amdgcn_exp2f(d * d * NL);
            d = cen - m1[k];     const float a2 = __builtin_amdgcn_exp2f(d * d * NL);
            d = cen - m2[k];     const float a3 = __builtin_amdgcn_exp2f(d * d * NL);
            d = cen - m1[k + 1]; const float b0 = __builtin_amdgcn_exp2f(d * d * NL);
            d = cen - m1[k + 2]; const float b1 = __builtin_amdgcn_exp2f(d * d * NL);
            d = cen - m2[k + 1]; const float b2 = __builtin_amdgcn_exp2f(d * d * NL);
            d = cen - m2[k + 2]; const float b3 = __builtin_amdgcn_exp2f(d * d * NL);
            const float s1 = (a0 + a1) + (a2 + a3);
            const float s2 = (b0 + b1) + (b2 + b3);
            const float fN = fmaf(E2N, s2, fmaf(E1N, s1, C9));   // first/9
            ov[k] = fmaf(w1a[k], fN, w2a[k] * W2C);
        }
        *reinterpret_cast<float4*>(op + q * S) = o;
    }
}

extern "C" void kernel_launch(void* const* d_in, const int* in_sizes, int n_in,
                              void* d_out, int out_size, void* d_ws, size_t ws_size,
                              hipStream_t stream) {
    const float* x  = (const float*)d_in[0];
    const float* w1 = (const float*)d_in[1];
    const float* w2 = (const float*)d_in[2];
    float* out = (float*)d_out;
    pairwise_potential_kernel<<<NBLOCKS, 256, 0, stream>>>(x, w1, w2, out);
}